// Round 1
// 269.602 us; speedup vs baseline: 1.1658x; 1.1658x over previous
//
#include <hip/hip_runtime.h>

// LSTM B=65536, L=6, H=50, T=3, IN=3, FC 50->1 — fp16 MFMA, R8.
//
// R8 vs R7 (189us kernel: VALU-issue-bound, 45% busy, phase-lockstep stalls):
//  - Software-pipelined x-part: gates_t = Wx*x_t + Wh*h_{t-1}. The x-part of
//    step t+1 (src buffer, stable all layer) is computed right after step t's
//    activations free the accumulators -> MFMA issue overlaps the activation/
//    barrier window; post-barrier dependent chain is 2 slabs, not 4. No extra
//    acc registers (per-mt lifetimes disjoint).
//  - Acc zeroing eliminated: first MFMA of each chain takes C = persistent
//    zero quad (D != C, no copy).
//  - Weights prescaled in wprep: i,f,o rows by 1/ln2, g row by 2/ln2
//    (tanh x = 2*sigm(2x)-1) -> sigmoid = rcp(1+exp2(-g)), negate is a free
//    src modifier. Saves 4 VALU/unit.
//  - Pair-packed staging (half2/b64, immediate offsets): k in [50,64) pad+bias
//    written ONCE at start (invariant; h-writes only touch j<50); x staged as
//    2 b32 + 7 b64 per row; h0 staged as 4x {dwordx2, cvt, b32}.
//  - Layer-0 x-slab s=1 skipped (W==0 there; k in [32,50) of x slots left
//    uninitialized but provably never read).
// Layout unchanged: gates^T = W*X^T, n = 4j+gate; lane holds all 4 gates of
// unit j = 4*ntg+q (lane-local c/h update). One barrier per step.

namespace {

constexpr int H  = 50;
constexpr int L  = 6;
constexpr int T  = 3;
constexpr int IN = 3;
constexpr int M  = 64;     // samples per block (4 m-tiles)
constexpr int BLK = 512;   // 8 waves
constexpr int ROWS = 72;   // _Float16 row stride (144 B)

using half8  = __attribute__((ext_vector_type(8))) _Float16;
using half2v = __attribute__((ext_vector_type(2))) _Float16;
using f32x4  = __attribute__((ext_vector_type(4))) float;

__device__ __forceinline__ float rcp_(float x) { return __builtin_amdgcn_rcpf(x); }
__device__ __forceinline__ float ex2(float x)  { return __builtin_amdgcn_exp2f(x); }

// ---------------- prologue: pack fp16 A-fragments, prescaled ----------------
// frag id f = (l*4 + s)*16 + nt ; lane's frag: W[n=16*nt+(lam&15)][k=32*s+(lam>>4)*8+jj]
// Rows prescaled: gate g (n&3==2) by 2/ln2, others by 1/ln2 (bias included).
__global__ void wprep(const float* __restrict__ w_ih0, const float* __restrict__ w_ihL,
                      const float* __restrict__ w_hh,  const float* __restrict__ b_ih,
                      const float* __restrict__ b_hh,  _Float16* __restrict__ wbuf) {
  int t = blockIdx.x * 256 + threadIdx.x;
  if (t >= 384 * 64) return;
  int lam = t & 63, f = t >> 6;
  int nt = f & 15, s = (f >> 4) & 3, l = f >> 6;
  int n = nt * 16 + (lam & 15);
  int j = n >> 2, gate = n & 3, row = gate * 50 + j;  // PyTorch gate order i,f,g,o
  float scale = (gate == 2) ? 2.8853900817779268f : 1.4426950408889634f;
  _Float16 o8[8];
#pragma unroll
  for (int jj = 0; jj < 8; ++jj) {
    int k = s * 32 + (lam >> 4) * 8 + jj;
    float v = 0.f;
    if (j < H) {
      if (s < 2) {                       // x-part, k in [0,64)
        int ksz = (l == 0) ? IN : H;
        if (k < ksz) v = (l == 0) ? w_ih0[row * IN + k]
                                  : w_ihL[((size_t)(l - 1) * 200 + row) * H + k];
      } else {                           // h-part
        int kh = k - 64;
        if (kh < H)        v = w_hh[((size_t)l * 200 + row) * H + kh];
        else if (kh == 63) v = b_ih[l * 200 + row] + b_hh[l * 200 + row];  // bias
      }
    }
    o8[jj] = (_Float16)(v * scale);
  }
  ((half8*)wbuf)[t] = *(half8*)o8;
}

// ---------------- main kernel ----------------
__global__ __launch_bounds__(BLK, 4)   // cap 128 combined regs -> 2 blocks/CU
void lstm_mfma(const float* __restrict__ x,   const float* __restrict__ h0,
               const float* __restrict__ c0,  const float* __restrict__ fc_w,
               const float* __restrict__ fc_b, const _Float16* __restrict__ wbuf,
               float* __restrict__ out, int B) {
  const int tid = threadIdx.x;
  const int lam = tid & 63;
  const int q   = lam >> 4;
  const int lm  = lam & 15;
  const int bbase = blockIdx.x * M;
  const int ng  = __builtin_amdgcn_readfirstlane(tid >> 6);
  const int ntp = __builtin_amdgcn_readfirstlane((ng + blockIdx.x) & 7);  // pad-wave rotation
  const int ntg0 = 2 * ntp, ntg1 = 2 * ntp + 1;
  const bool live0 = (ntg0 <= 12);          // tiles 13..15 are pure padding (j>=52)
  const bool live1 = (ntg1 <= 12);

  __shared__ __align__(16) _Float16 ys[2][T][M][ROWS];

  // ---- staging: x pairs k<4 + zeros k[4,32) into ys[0]; k[50,64) consts into
  //      all 6 slots (written once; h-writes/h0-stage never touch k>=50) ----
  if (tid < T * M) {                         // 192 threads, one (t,m) row each
    const int t = tid >> 6, m = tid & 63;
    const float* xs = x + (size_t)(bbase + m) * (IN * T) + t;
    _Float16* row = &ys[0][t][m][0];
    half2v p0; p0[0] = (_Float16)xs[0]; p0[1] = (_Float16)xs[3];
    half2v p1; p1[0] = (_Float16)xs[6]; p1[1] = (_Float16)0.f;
    *(half2v*)(row)     = p0;
    *(half2v*)(row + 2) = p1;
#pragma unroll
    for (int z = 0; z < 7; ++z)              // k in [4,32) := 0 (layer-0 slab 0 pad)
      *(unsigned long long*)(row + 4 + 4 * z) = 0ull;
  }
  if (tid < 2 * T * M) {                     // 384 rows: k in [50,64) pad + bias col
    _Float16* row = &ys[0][0][0][0] + (size_t)tid * ROWS;
#pragma unroll
    for (int z = 0; z < 6; ++z)
      *(unsigned int*)(row + 50 + 2 * z) = 0u;
    half2v pb; pb[0] = (_Float16)0.f; pb[1] = (_Float16)1.f;   // k63 = 1.0 (bias)
    *(half2v*)(row + 62) = pb;
  }
  __syncthreads();

  float cc[2][4];
  f32x4 xa[2][4];                            // x-part acc, h-part accumulates in
  half8 W[2][4];                             // [nt][kslab] — 32 regs
  const f32x4 z4 = {0.f, 0.f, 0.f, 0.f};

  for (int l = 0; l < L; ++l) {
    const int sb = l & 1, db = sb ^ 1;
    _Float16 (*src)[M][ROWS] = ys[sb];
    _Float16 (*dst)[M][ROWS] = ys[db];

    // ---- c0 straight to registers (dead tiles skipped) ----
#pragma unroll
    for (int nt = 0; nt < 2; ++nt) {
      const int ntg = nt ? ntg1 : ntg0;
      const bool lv = nt ? live1 : live0;
      const int j = 4 * ntg + q;
#pragma unroll
      for (int mt = 0; mt < 4; ++mt)
        cc[nt][mt] = (lv && j < H)
            ? c0[((size_t)l * B + bbase + mt * 16 + lm) * H + j] : 0.f;
    }
    // ---- W fragments for this layer (live tiles only, coalesced dwordx4) ----
#pragma unroll
    for (int nt = 0; nt < 2; ++nt) {
      const int ntg = nt ? ntg1 : ntg0;
      const bool lv = nt ? live1 : live0;
      if (lv)
#pragma unroll
        for (int s = 0; s < 4; ++s)
          W[nt][s] = ((const half8*)wbuf)[((l * 4 + s) * 16 + ntg) * 64 + lam];
    }

    // ---- x-part of t=0 (src stable since prev barrier; overlaps h0 staging) --
    if (live0) {
#pragma unroll
      for (int s = 0; s < 2; ++s) {
        if (s == 1 && l == 0) continue;       // W==0 slab (and avoids uninit LDS)
        half8 Xf[4];
#pragma unroll
        for (int mt = 0; mt < 4; ++mt)
          Xf[mt] = *(const half8*)(&src[0][mt * 16 + lm][s * 32 + q * 8]);
#pragma unroll
        for (int mt = 0; mt < 4; ++mt)
          xa[0][mt] = __builtin_amdgcn_mfma_f32_16x16x32_f16(
              W[0][s], Xf[mt], s == 0 ? z4 : xa[0][mt], 0, 0, 0);
        if (live1)
#pragma unroll
          for (int mt = 0; mt < 4; ++mt)
            xa[1][mt] = __builtin_amdgcn_mfma_f32_16x16x32_f16(
                W[1][s], Xf[mt], s == 0 ? z4 : xa[1][mt], 0, 0, 0);
      }
    }

    // ---- stage h0 into dst[T-1], pair-packed (k<50; k>=50 is invariant) ----
    {
      const int mg = tid >> 3, kpl = tid & 7;             // 8 threads per row
      const float* hp = h0 + ((size_t)l * B + bbase + mg) * H + 2 * kpl;
      _Float16* dp = &dst[T - 1][mg][2 * kpl];
#pragma unroll
      for (int it = 0; it < 4; ++it) {
        if (it < 3 || kpl == 0) {                         // kp = kpl+8it < 25
          float2 v = *(const float2*)(hp + 16 * it);
          half2v pv; pv[0] = (_Float16)v.x; pv[1] = (_Float16)v.y;
          *(half2v*)(dp + 16 * it) = pv;
        }
      }
    }
    __syncthreads();

#pragma unroll
    for (int t = 0; t < T; ++t) {
      const int hsl = (t == 0) ? T - 1 : t - 1;           // h-source slot in dst buf
      if (live0) {                                        // all-dead wave skips compute
        // ---- h-part (slabs 2,3) accumulates onto prefetched x-part ----
#pragma unroll
        for (int s = 0; s < 2; ++s) {
          half8 Xf[4];
#pragma unroll
          for (int mt = 0; mt < 4; ++mt)
            Xf[mt] = *(const half8*)(&dst[hsl][mt * 16 + lm][s * 32 + q * 8]);
#pragma unroll
          for (int mt = 0; mt < 4; ++mt)
            xa[0][mt] = __builtin_amdgcn_mfma_f32_16x16x32_f16(
                W[0][s + 2], Xf[mt], xa[0][mt], 0, 0, 0);
          if (live1)
#pragma unroll
            for (int mt = 0; mt < 4; ++mt)
              xa[1][mt] = __builtin_amdgcn_mfma_f32_16x16x32_f16(
                  W[1][s + 2], Xf[mt], xa[1][mt], 0, 0, 0);
        }

        // ---- activations: gates prescaled -> sigm = rcp(1+exp2(-g)) ----
#pragma unroll
        for (int nt = 0; nt < 2; ++nt) {
          if (nt && !live1) continue;
          const int ntg = nt ? ntg1 : ntg0;
          const int j = 4 * ntg + q;
#pragma unroll
          for (int mt = 0; mt < 4; ++mt) {
            const float ig = rcp_(1.f + ex2(-xa[nt][mt][0]));
            const float fg = rcp_(1.f + ex2(-xa[nt][mt][1]));
            const float gg = 2.f * rcp_(1.f + ex2(-xa[nt][mt][2])) - 1.f;
            const float og = rcp_(1.f + ex2(-xa[nt][mt][3]));
            const float cv = fg * cc[nt][mt] + ig * gg;
            cc[nt][mt] = cv;
            const float tc = 2.f * rcp_(1.f + ex2(-2.8853900817779268f * cv)) - 1.f;
            const float hv = og * tc;
            if (j < H)                        // keep pad cols (and k63=1.0) intact
              dst[t][mt * 16 + lm][j] = (_Float16)hv;
          }
        }

        // ---- x-part prefetch for t+1 (src stable; fills barrier window) ----
        if (t < T - 1) {
#pragma unroll
          for (int s = 0; s < 2; ++s) {
            if (s == 1 && l == 0) continue;
            half8 Xf[4];
#pragma unroll
            for (int mt = 0; mt < 4; ++mt)
              Xf[mt] = *(const half8*)(&src[t + 1][mt * 16 + lm][s * 32 + q * 8]);
#pragma unroll
            for (int mt = 0; mt < 4; ++mt)
              xa[0][mt] = __builtin_amdgcn_mfma_f32_16x16x32_f16(
                  W[0][s], Xf[mt], s == 0 ? z4 : xa[0][mt], 0, 0, 0);
            if (live1)
#pragma unroll
              for (int mt = 0; mt < 4; ++mt)
                xa[1][mt] = __builtin_amdgcn_mfma_f32_16x16x32_f16(
                    W[1][s], Xf[mt], s == 0 ? z4 : xa[1][mt], 0, 0, 0);
          }
        }
      }
      __syncthreads();   // h_t (and, at t=T-1, layer output) visible
    }
  }

  // ---- fc tail: out[b] = fc_w · h_last + fc_b ; final dst buffer = ys[0] ----
  {
    int m = tid >> 3, strip = tid & 7;
    float part = 0.f;
#pragma unroll
    for (int jj = 0; jj < 7; ++jj) {
      int j = strip + 8 * jj;
      if (j < H) part += fc_w[j] * (float)ys[0][T - 1][m][j];
    }
    part += __shfl_xor(part, 4);
    part += __shfl_xor(part, 2);
    part += __shfl_xor(part, 1);
    if (strip == 0) out[bbase + m] = part + fc_b[0];
  }
}

}  // namespace

extern "C" void kernel_launch(void* const* d_in, const int* in_sizes, int n_in,
                              void* d_out, int out_size, void* d_ws, size_t ws_size,
                              hipStream_t stream) {
  const float* x     = (const float*)d_in[0];
  const float* h0    = (const float*)d_in[1];
  const float* c0    = (const float*)d_in[2];
  const float* w_ih0 = (const float*)d_in[3];
  const float* w_ih  = (const float*)d_in[4];
  const float* w_hh  = (const float*)d_in[5];
  const float* b_ih  = (const float*)d_in[6];
  const float* b_hh  = (const float*)d_in[7];
  const float* fc_w  = (const float*)d_in[8];
  const float* fc_b  = (const float*)d_in[9];
  float* out         = (float*)d_out;

  const int B = in_sizes[0] / (IN * T);  // 65536
  _Float16* wbuf = (_Float16*)d_ws;      // 384 frags * 64 lanes * 16 B = 393 KB

  wprep<<<(384 * 64 + 255) / 256, 256, 0, stream>>>(w_ih0, w_ih, w_hh, b_ih, b_hh, wbuf);
  lstm_mfma<<<B / M, BLK, 0, stream>>>(x, h0, c0, fc_w, fc_b, wbuf, out, B);
}